// Round 11
// baseline (393.541 us; speedup 1.0000x reference)
//
#include <hip/hip_runtime.h>
#include <hip/hip_bf16.h>

#define NN 100000
#define EE 1200000
#define F1 128
#define F2 256
#define F3 40
#define MROWS 64
#define NBUK ((NN + 255) / 256)          // 391 coarse buckets (256 nodes each)
#define NBLK 256                         // radix blocks
#define CHUNK ((EE + NBLK - 1) / NBLK)   // 4688 edges per block
#define DCAP 4096                        // max records per bucket (mean 3070, +18 sigma)
#define WB ((F1 * F2 + F2 * 48 + 255) / 256)   // weight-pack blocks appended to k_csr

typedef __bf16 bf16x8 __attribute__((ext_vector_type(8)));
typedef float  f32x4  __attribute__((ext_vector_type(4)));

__device__ __forceinline__ unsigned short f2bf(float f) {   // RNE bf16
    unsigned u = __float_as_uint(f);
    return (unsigned short)((u + 0x7fffu + ((u >> 16) & 1u)) >> 16);
}
__device__ __forceinline__ float bflo(unsigned v) { return __uint_as_float(v << 16); }
__device__ __forceinline__ float bfhi(unsigned v) { return __uint_as_float(v & 0xffff0000u); }

// ---- pass A: per-(block,bin) coarse histogram, int4 edge loads ----
__global__ __launch_bounds__(256) void k_hist(const int* __restrict__ col,
                                              int* __restrict__ hist) {
    __shared__ int lh[NBUK];
    for (int i = threadIdx.x; i < NBUK; i += 256) lh[i] = 0;
    __syncthreads();
    int e0 = blockIdx.x * CHUNK;
    int e1 = min(e0 + CHUNK, EE);
    for (int e = e0 + threadIdx.x * 4; e + 3 < e1; e += 1024) {
        int4 c = *(const int4*)(col + e);
        if ((unsigned)c.x < (unsigned)NN) atomicAdd(&lh[c.x >> 8], 1);
        if ((unsigned)c.y < (unsigned)NN) atomicAdd(&lh[c.y >> 8], 1);
        if ((unsigned)c.z < (unsigned)NN) atomicAdd(&lh[c.z >> 8], 1);
        if ((unsigned)c.w < (unsigned)NN) atomicAdd(&lh[c.w >> 8], 1);
    }
    __syncthreads();
    for (int i = threadIdx.x; i < NBUK; i += 256) hist[blockIdx.x * NBUK + i] = lh[i];
}

// ---- pass B1: scan each bin's 256 per-block counts ----
__global__ __launch_bounds__(256) void k_scanbin(int* __restrict__ hist,
                                                 int* __restrict__ bintot) {
    __shared__ int s[NBLK];
    int b = blockIdx.x;
    int v = hist[threadIdx.x * NBUK + b];
    s[threadIdx.x] = v;
    __syncthreads();
    int acc = v;
    for (int d = 1; d < NBLK; d <<= 1) {
        int add = (threadIdx.x >= d) ? s[threadIdx.x - d] : 0;
        __syncthreads();
        acc += add;
        s[threadIdx.x] = acc;
        __syncthreads();
    }
    hist[threadIdx.x * NBUK + b] = acc - v;
    if (threadIdx.x == NBLK - 1) bintot[b] = acc;
}

// ---- pass B2: exclusive scan of bin totals -> binbase[NBUK+1] ----
__global__ __launch_bounds__(512) void k_scanbase(const int* __restrict__ bintot,
                                                  int* __restrict__ binbase) {
    __shared__ int s[512];
    int v = (threadIdx.x < NBUK) ? bintot[threadIdx.x] : 0;
    s[threadIdx.x] = v;
    __syncthreads();
    int acc = v;
    for (int d = 1; d < 512; d <<= 1) {
        int add = (threadIdx.x >= d) ? s[threadIdx.x - d] : 0;
        __syncthreads();
        acc += add;
        s[threadIdx.x] = acc;
        __syncthreads();
    }
    if (threadIdx.x < NBUK) binbase[threadIdx.x] = acc - v;
    if (threadIdx.x == NBUK - 1) binbase[NBUK] = acc;
}

// ---- pass C: scatter records into block-private runs per bin ----
__global__ __launch_bounds__(256) void k_scat(const int* __restrict__ row,
                                              const int* __restrict__ col,
                                              const int* __restrict__ hist,
                                              const int* __restrict__ binbase,
                                              unsigned* __restrict__ rec) {
    __shared__ int lcur[NBUK];
    for (int i = threadIdx.x; i < NBUK; i += 256)
        lcur[i] = binbase[i] + hist[blockIdx.x * NBUK + i];
    __syncthreads();
    int e0 = blockIdx.x * CHUNK;
    int e1 = min(e0 + CHUNK, EE);
    for (int e = e0 + threadIdx.x * 4; e + 3 < e1; e += 1024) {
        int4 r = *(const int4*)(row + e);
        int4 c = *(const int4*)(col + e);
        if ((unsigned)c.x < (unsigned)NN) {
            int p = atomicAdd(&lcur[c.x >> 8], 1);
            rec[p] = ((unsigned)r.x & 0xFFFFFFu) | ((unsigned)(c.x & 255) << 24);
        }
        if ((unsigned)c.y < (unsigned)NN) {
            int p = atomicAdd(&lcur[c.y >> 8], 1);
            rec[p] = ((unsigned)r.y & 0xFFFFFFu) | ((unsigned)(c.y & 255) << 24);
        }
        if ((unsigned)c.z < (unsigned)NN) {
            int p = atomicAdd(&lcur[c.z >> 8], 1);
            rec[p] = ((unsigned)r.z & 0xFFFFFFu) | ((unsigned)(c.z & 255) << 24);
        }
        if ((unsigned)c.w < (unsigned)NN) {
            int p = atomicAdd(&lcur[c.w >> 8], 1);
            rec[p] = ((unsigned)r.w & 0xFFFFFFu) | ((unsigned)(c.w & 255) << 24);
        }
    }
}

// ---- pass D: bucket -> CSR + cnt/cursor/dinv + own-node x->xh prep; extra
//      blocks pack W1/W2 ----
__global__ __launch_bounds__(256) void k_csr(const int* __restrict__ binbase,
                                             const unsigned* __restrict__ rec,
                                             int* __restrict__ eidx,
                                             int* __restrict__ cnt,
                                             int* __restrict__ cursor,
                                             float* __restrict__ dinv,
                                             const float4* __restrict__ x4,
                                             unsigned* __restrict__ xh,
                                             const float* __restrict__ W1,
                                             const float* __restrict__ W2,
                                             __hip_bfloat16* __restrict__ W1p,
                                             __hip_bfloat16* __restrict__ W2p) {
    if (blockIdx.x >= NBUK) {   // weight packing (block-uniform branch, no syncs)
        int idx = (blockIdx.x - NBUK) * 256 + threadIdx.x;
        if (idx < F1 * F2) {
            int k = idx / F2, colw = idx - (idx / F2) * F2;
            int k8 = k >> 3, j = k & 7;
            W1p[((size_t)(k8 * F2 + colw) << 3) + j] = __float2bfloat16(W1[(size_t)k * F2 + colw]);
        } else if (idx < F1 * F2 + F2 * 48) {
            int i2 = idx - F1 * F2;
            int k = i2 / 48, colw = i2 - (i2 / 48) * 48;
            int k8 = k >> 3, j = k & 7;
            float v = (colw < F3) ? W2[(size_t)k * F3 + colw] : 0.0f;
            W2p[((size_t)(k8 * 48 + colw) << 3) + j] = __float2bfloat16(v);
        }
        return;
    }
    __shared__ int lcnt[256];
    __shared__ int s[256];
    __shared__ int lcur[256];
    __shared__ float sdinv[256];
    __shared__ int lde[DCAP];
    const int b = blockIdx.x;
    const int tid = threadIdx.x;
    lcnt[tid] = 0;
    __syncthreads();
    const int base = binbase[b];
    const int nb = min(binbase[b + 1] - base, DCAP);
    for (int j = tid; j < nb; j += 256) atomicAdd(&lcnt[rec[base + j] >> 24], 1);
    __syncthreads();
    int cv = lcnt[tid];
    s[tid] = cv;
    __syncthreads();
    int acc = cv;
    for (int d = 1; d < 256; d <<= 1) {
        int add = (tid >= d) ? s[tid - d] : 0;
        __syncthreads();
        acc += add;
        s[tid] = acc;
        __syncthreads();
    }
    int excl = acc - cv;
    lcur[tid] = excl;
    const int node = (b << 8) + tid;
    float dv = rsqrtf((float)(cv + 1));
    sdinv[tid] = dv;
    if (node < NN) {
        cnt[node] = cv;
        cursor[node] = base + excl + cv;            // END cursor (start = end - cnt)
        dinv[node] = dv;                            // +1 self-loop
    }
    __syncthreads();
    for (int j = tid; j < nb; j += 256) {
        unsigned v = rec[base + j];
        int pos = atomicAdd(&lcur[v >> 24], 1);     // LDS atomic
        lde[pos] = (int)(v & 0xFFFFFFu);
    }
    __syncthreads();
    for (int j = tid; j < nb; j += 256) eidx[base + j] = lde[j];
    // own-node prescale: xh[node] = bf16(x[node] * dinv[node])
    for (int j = tid; j < 256 * 32; j += 256) {
        int nl = j >> 5;
        int gn = (b << 8) + nl;
        if (gn < NN) {
            float d = sdinv[nl];
            float4 v = x4[(size_t)gn * 32 + (j & 31)];
            uint2 o;
            o.x = (unsigned)f2bf(v.x * d) | ((unsigned)f2bf(v.y * d) << 16);
            o.y = (unsigned)f2bf(v.z * d) | ((unsigned)f2bf(v.w * d) << 16);
            *(uint2*)(xh + ((size_t)gn << 6) + ((j & 31) << 1)) = o;
        }
    }
}

// ---- FUSED: layer-1 gather-aggregate (into LDS) + MFMA GEMM1+ReLU+GEMM2 ----
// 64 nodes/block; wave w aggregates nodes w*16..w*16+15 via 4x16-lane groups.
__global__ __launch_bounds__(256) void k_fused(const int* __restrict__ cursor,
                                               const int* __restrict__ cnt,
                                               const int* __restrict__ eidx,
                                               const float* __restrict__ dinv,
                                               const unsigned* __restrict__ xh,
                                               const __hip_bfloat16* __restrict__ W1p,
                                               const float* __restrict__ b1,
                                               const __hip_bfloat16* __restrict__ W2p,
                                               unsigned short* __restrict__ tg) {
    __shared__ __hip_bfloat16 a_s[MROWS][F1 + 8];   // +8: rows land 2-way on banks (free)
    __shared__ __hip_bfloat16 h_s[MROWS][F2 + 8];
    const int i0   = blockIdx.x * MROWS;
    const int wave = threadIdx.x >> 6;
    const int lane = threadIdx.x & 63;
    const int g = lane >> 4;      // edge sub-slot 0..3
    const int l = lane & 15;      // dwords 4l..4l+3 = features 8l..8l+7

    // ---- phase 1: aggregate 16 nodes per wave ----
#pragma unroll 1
    for (int t = 0; t < 16; ++t) {
        const int node = i0 + (wave << 4) + t;
        float a0 = 0.f, a1 = 0.f, a2 = 0.f, a3 = 0.f,
              a4 = 0.f, a5 = 0.f, a6 = 0.f, a7 = 0.f;
        if (node < NN) {
            if (g == 0) {
                uint4 v = *(const uint4*)(xh + ((size_t)node << 6) + (l << 2));
                a0 = bflo(v.x); a1 = bfhi(v.x); a2 = bflo(v.y); a3 = bfhi(v.y);
                a4 = bflo(v.z); a5 = bfhi(v.z); a6 = bflo(v.w); a7 = bfhi(v.w);
            }
            int n = cnt[node];
            int s = cursor[node] - n;
            int k = 0;
            for (; k + 7 < n; k += 8) {
                int r0 = eidx[s + k + g];
                int r1 = eidx[s + k + 4 + g];
                uint4 v0 = *(const uint4*)(xh + ((size_t)r0 << 6) + (l << 2));
                uint4 v1 = *(const uint4*)(xh + ((size_t)r1 << 6) + (l << 2));
                a0 += bflo(v0.x); a1 += bfhi(v0.x); a2 += bflo(v0.y); a3 += bfhi(v0.y);
                a4 += bflo(v0.z); a5 += bfhi(v0.z); a6 += bflo(v0.w); a7 += bfhi(v0.w);
                a0 += bflo(v1.x); a1 += bfhi(v1.x); a2 += bflo(v1.y); a3 += bfhi(v1.y);
                a4 += bflo(v1.z); a5 += bfhi(v1.z); a6 += bflo(v1.w); a7 += bfhi(v1.w);
            }
            for (; k < n; k += 4) {
                if (k + g < n) {
                    int r0 = eidx[s + k + g];
                    uint4 v0 = *(const uint4*)(xh + ((size_t)r0 << 6) + (l << 2));
                    a0 += bflo(v0.x); a1 += bfhi(v0.x); a2 += bflo(v0.y); a3 += bfhi(v0.y);
                    a4 += bflo(v0.z); a5 += bfhi(v0.z); a6 += bflo(v0.w); a7 += bfhi(v0.w);
                }
            }
        }
        a0 += __shfl_down(a0, 32, 64); a1 += __shfl_down(a1, 32, 64);
        a2 += __shfl_down(a2, 32, 64); a3 += __shfl_down(a3, 32, 64);
        a4 += __shfl_down(a4, 32, 64); a5 += __shfl_down(a5, 32, 64);
        a6 += __shfl_down(a6, 32, 64); a7 += __shfl_down(a7, 32, 64);
        a0 += __shfl_down(a0, 16, 64); a1 += __shfl_down(a1, 16, 64);
        a2 += __shfl_down(a2, 16, 64); a3 += __shfl_down(a3, 16, 64);
        a4 += __shfl_down(a4, 16, 64); a5 += __shfl_down(a5, 16, 64);
        a6 += __shfl_down(a6, 16, 64); a7 += __shfl_down(a7, 16, 64);
        if (g == 0) {
            float d = (node < NN) ? dinv[node] : 0.0f;
            uint4 o;
            o.x = (unsigned)f2bf(a0 * d) | ((unsigned)f2bf(a1 * d) << 16);
            o.y = (unsigned)f2bf(a2 * d) | ((unsigned)f2bf(a3 * d) << 16);
            o.z = (unsigned)f2bf(a4 * d) | ((unsigned)f2bf(a5 * d) << 16);
            o.w = (unsigned)f2bf(a6 * d) | ((unsigned)f2bf(a7 * d) << 16);
            *(uint4*)(&a_s[(wave << 4) + t][l << 3]) = o;
        }
    }
    __syncthreads();

    // ---- phase 2: GEMM1 + ReLU (A from LDS) ----
    const int m = lane & 15, q = lane >> 4;
    f32x4 acc[16];
#pragma unroll
    for (int c = 0; c < 16; ++c) acc[c] = (f32x4){0.f, 0.f, 0.f, 0.f};

#pragma unroll
    for (int s = 0; s < 4; ++s) {           // k = 32s + 8q + j
        bf16x8 a = *(const bf16x8*)(&a_s[(wave << 4) + m][s * 32 + q * 8]);
        const __hip_bfloat16* bp = W1p + ((size_t)(4 * s + q) * F2) * 8;
#pragma unroll
        for (int c = 0; c < 16; ++c) {
            bf16x8 b = *(const bf16x8*)(bp + ((size_t)(c * 16 + m) << 3));
            acc[c] = __builtin_amdgcn_mfma_f32_16x16x32_bf16(a, b, acc[c], 0, 0, 0);
        }
    }

#pragma unroll
    for (int c = 0; c < 16; ++c) {
        int col = c * 16 + m;
        float bj = b1[col];
#pragma unroll
        for (int r = 0; r < 4; ++r) {
            int lr = (wave << 4) + q * 4 + r;
            h_s[lr][col] = __float2bfloat16(fmaxf(acc[c][r] + bj, 0.0f));
        }
    }
    __syncthreads();

    // ---- phase 3: GEMM2, store tg = (h@W2)*dinv as padded bf16 rows ----
    f32x4 acc2[3];
#pragma unroll
    for (int c = 0; c < 3; ++c) acc2[c] = (f32x4){0.f, 0.f, 0.f, 0.f};

#pragma unroll
    for (int s = 0; s < 8; ++s) {
        bf16x8 a = *(const bf16x8*)(&h_s[(wave << 4) + m][s * 32 + q * 8]);
        const __hip_bfloat16* bp = W2p + ((size_t)(4 * s + q) * 48) * 8;
#pragma unroll
        for (int c = 0; c < 3; ++c) {
            bf16x8 b = *(const bf16x8*)(bp + ((size_t)(c * 16 + m) << 3));
            acc2[c] = __builtin_amdgcn_mfma_f32_16x16x32_bf16(a, b, acc2[c], 0, 0, 0);
        }
    }

#pragma unroll
    for (int c = 0; c < 3; ++c) {
        int col = c * 16 + m;
        if (col < F3) {
#pragma unroll
            for (int r = 0; r < 4; ++r) {
                int grow = i0 + (wave << 4) + q * 4 + r;
                if (grow < NN)
                    tg[((size_t)grow << 6) + col] = f2bf(acc2[c][r] * dinv[grow]);
            }
        }
    }
}

// ---- layer-2 pull: 3x20-lane groups, dword/lane => 6 rows in flight ----
__global__ __launch_bounds__(256) void k_agg2(const int* __restrict__ cursor,
                                              const int* __restrict__ cnt,
                                              const int* __restrict__ eidx,
                                              const float* __restrict__ dinv,
                                              const unsigned* __restrict__ tg32,
                                              const float* __restrict__ b2,
                                              float* __restrict__ out) {
    int node = blockIdx.x * 4 + (threadIdx.x >> 6);
    int lane = threadIdx.x & 63;
    if (node >= NN) return;
    const int g = lane / 20;
    const int l = lane - g * 20;
    const bool act = g < 3;
    float a0 = 0.f, a1 = 0.f;
    if (g == 0) {
        unsigned v = tg32[((size_t)node << 5) + l];
        a0 = bflo(v); a1 = bfhi(v);
    }
    int n = cnt[node];
    int s = cursor[node] - n;
    int k = 0;
    for (; k + 5 < n; k += 6) {
        unsigned v0 = 0u, v1 = 0u;
        if (act) {
            int r0 = eidx[s + k + g];
            int r1 = eidx[s + k + 3 + g];
            v0 = tg32[((size_t)r0 << 5) + l];
            v1 = tg32[((size_t)r1 << 5) + l];
        }
        a0 += bflo(v0); a1 += bfhi(v0);
        a0 += bflo(v1); a1 += bfhi(v1);
    }
    for (; k < n; k += 3) {
        if (act && (k + g) < n) {
            int r0 = eidx[s + k + g];
            unsigned v0 = tg32[((size_t)r0 << 5) + l];
            a0 += bflo(v0); a1 += bfhi(v0);
        }
    }
    float t0a = __shfl_down(a0, 20, 64), t0b = __shfl_down(a0, 40, 64);
    float t1a = __shfl_down(a1, 20, 64), t1b = __shfl_down(a1, 40, 64);
    if (lane < 20) {
        float d = dinv[node];
        float o0 = d * (a0 + t0a + t0b) + b2[2 * lane];
        float o1 = d * (a1 + t1a + t1b) + b2[2 * lane + 1];
        float2 o = {o0, o1};
        *(float2*)(out + (size_t)node * F3 + (lane << 1)) = o;
    }
}

extern "C" void kernel_launch(void* const* d_in, const int* in_sizes, int n_in,
                              void* d_out, int out_size, void* d_ws, size_t ws_size,
                              hipStream_t stream) {
    const float* x  = (const float*)d_in[0];
    const int*   ei = (const int*)d_in[1];
    const float* W1 = (const float*)d_in[2];
    const float* b1 = (const float*)d_in[3];
    const float* W2 = (const float*)d_in[4];
    const float* b2 = (const float*)d_in[5];
    float* out = (float*)d_out;

    const int* row = ei;
    const int* col = ei + EE;

    // ws: cnt[N] | cursor[N] | dinv[N] | hist[NBLK*NBUK] | bintot | binbase
    //     | eidx[E] | xh[N*64 u32] | tg[N*64 bf16] | W1p | W2p        ~45 MB
    // overlay: rec (E u32 = 4.8 MB) on tg (12.8 MB) — rec is consumed by k_csr
    // before k_fused writes tg.
    int* cnt     = (int*)d_ws;
    int* cursor  = cnt + NN;
    float* dinv  = (float*)(cursor + NN);
    int* hist    = (int*)(dinv + NN);
    int* bintot  = hist + NBLK * NBUK;
    int* binbase = bintot + NBUK;
    int* eidx    = binbase + (NBUK + 1) + 7;   // alignment slack
    unsigned* xh = (unsigned*)(eidx + EE);
    unsigned short* tg = (unsigned short*)(xh + (size_t)NN * 64);
    unsigned* rec = (unsigned*)tg;                     // overlay (sequential use)
    __hip_bfloat16* W1p = (__hip_bfloat16*)(tg + (size_t)NN * 64);
    __hip_bfloat16* W2p = W1p + (size_t)F1 * F2;

    k_hist    <<<NBLK, 256, 0, stream>>>(col, hist);
    k_scanbin <<<NBUK, NBLK, 0, stream>>>(hist, bintot);
    k_scanbase<<<1, 512, 0, stream>>>(bintot, binbase);
    k_scat    <<<NBLK, 256, 0, stream>>>(row, col, hist, binbase, rec);
    k_csr     <<<NBUK + WB, 256, 0, stream>>>(binbase, rec, eidx, cnt, cursor, dinv,
                                              (const float4*)x, xh, W1, W2, W1p, W2p);

    k_fused<<<(NN + MROWS - 1) / MROWS, 256, 0, stream>>>(
        cursor, cnt, eidx, dinv, xh, W1p, b1, W2p, tg);
    k_agg2<<<(NN + 3) / 4, 256, 0, stream>>>(cursor, cnt, eidx, dinv,
                                             (const unsigned*)tg, b2, out);
}

// Round 12
// 301.848 us; speedup vs baseline: 1.3038x; 1.3038x over previous
//
#include <hip/hip_runtime.h>
#include <hip/hip_bf16.h>

#define NN 100000
#define EE 1200000
#define F1 128
#define F2 256
#define F3 40
#define MROWS 64
#define NBUK ((NN + 255) / 256)          // 391 coarse buckets (256 nodes each)
#define NBLK 256                         // radix blocks
#define CHUNK ((EE + NBLK - 1) / NBLK)   // 4688 edges per block
#define DCAP 4096                        // max records per bucket (mean 3070, +18 sigma)
#define XB ((NN * 64 + 255) / 256)       // 25000 blocks for x-prep

typedef __bf16 bf16x8 __attribute__((ext_vector_type(8)));
typedef float  f32x4  __attribute__((ext_vector_type(4)));

__device__ __forceinline__ unsigned short f2bf(float f) {   // RNE bf16
    unsigned u = __float_as_uint(f);
    return (unsigned short)((u + 0x7fffu + ((u >> 16) & 1u)) >> 16);
}
__device__ __forceinline__ float bflo(unsigned v) { return __uint_as_float(v << 16); }
__device__ __forceinline__ float bfhi(unsigned v) { return __uint_as_float(v & 0xffff0000u); }

// ---- pass A: per-(bin,block) coarse histogram only (no global atomics) ----
__global__ __launch_bounds__(256) void k_hist(const int* __restrict__ col,
                                              int* __restrict__ hist) {
    __shared__ int lh[NBUK];
    for (int i = threadIdx.x; i < NBUK; i += 256) lh[i] = 0;
    __syncthreads();
    int e0 = blockIdx.x * CHUNK;
    int e1 = min(e0 + CHUNK, EE);
    for (int e = e0 + threadIdx.x; e < e1; e += 256) {
        int c = col[e];
        if ((unsigned)c < (unsigned)NN) atomicAdd(&lh[c >> 8], 1);
    }
    __syncthreads();
    for (int i = threadIdx.x; i < NBUK; i += 256) hist[i * NBLK + blockIdx.x] = lh[i];
}

// ---- pass B1: scan each bin's 256 per-block counts; bintot per bin ----
__global__ __launch_bounds__(256) void k_scanbin(int* __restrict__ hist,
                                                 int* __restrict__ bintot) {
    __shared__ int s[NBLK];
    int b = blockIdx.x;
    int v = hist[b * NBLK + threadIdx.x];
    s[threadIdx.x] = v;
    __syncthreads();
    int acc = v;
    for (int d = 1; d < NBLK; d <<= 1) {
        int add = (threadIdx.x >= d) ? s[threadIdx.x - d] : 0;
        __syncthreads();
        acc += add;
        s[threadIdx.x] = acc;
        __syncthreads();
    }
    hist[b * NBLK + threadIdx.x] = acc - v;   // exclusive within bin
    if (threadIdx.x == NBLK - 1) bintot[b] = acc;
}

// ---- pass B2: exclusive scan of bin totals -> binbase[NBUK+1] ----
__global__ __launch_bounds__(512) void k_scanbase(const int* __restrict__ bintot,
                                                  int* __restrict__ binbase) {
    __shared__ int s[512];
    int v = (threadIdx.x < NBUK) ? bintot[threadIdx.x] : 0;
    s[threadIdx.x] = v;
    __syncthreads();
    int acc = v;
    for (int d = 1; d < 512; d <<= 1) {
        int add = (threadIdx.x >= d) ? s[threadIdx.x - d] : 0;
        __syncthreads();
        acc += add;
        s[threadIdx.x] = acc;
        __syncthreads();
    }
    if (threadIdx.x < NBUK) binbase[threadIdx.x] = acc - v;
    if (threadIdx.x == NBUK - 1) binbase[NBUK] = acc;
}

// ---- pass C: scatter records into block-private runs per bin ----
__global__ __launch_bounds__(256) void k_scat(const int* __restrict__ row,
                                              const int* __restrict__ col,
                                              const int* __restrict__ hist,
                                              const int* __restrict__ binbase,
                                              unsigned* __restrict__ rec) {
    __shared__ int lcur[NBUK];
    for (int i = threadIdx.x; i < NBUK; i += 256)
        lcur[i] = binbase[i] + hist[i * NBLK + blockIdx.x];
    __syncthreads();
    int e0 = blockIdx.x * CHUNK;
    int e1 = min(e0 + CHUNK, EE);
    for (int e = e0 + threadIdx.x; e < e1; e += 256) {
        int r = row[e], c = col[e];
        if ((unsigned)c < (unsigned)NN) {
            int pos = atomicAdd(&lcur[c >> 8], 1);   // LDS atomic
            rec[pos] = ((unsigned)r & 0xFFFFFFu) | ((unsigned)(c & 255) << 24);
        }
    }
}

// ---- pass D: bucket -> CSR; derive cnt via LDS histogram; cursor(end) + dinv ----
__global__ __launch_bounds__(256) void k_csr(const int* __restrict__ binbase,
                                             const unsigned* __restrict__ rec,
                                             int* __restrict__ eidx,
                                             int* __restrict__ cnt,
                                             int* __restrict__ cursor,
                                             float* __restrict__ dinv) {
    __shared__ int lcnt[256];
    __shared__ int s[256];
    __shared__ int lcur[256];
    __shared__ int lde[DCAP];
    const int b = blockIdx.x;
    const int tid = threadIdx.x;
    lcnt[tid] = 0;
    __syncthreads();
    const int base = binbase[b];
    const int nb = min(binbase[b + 1] - base, DCAP);
    for (int j = tid; j < nb; j += 256) atomicAdd(&lcnt[rec[base + j] >> 24], 1);
    __syncthreads();
    int cv = lcnt[tid];
    s[tid] = cv;
    __syncthreads();
    int acc = cv;
    for (int d = 1; d < 256; d <<= 1) {
        int add = (tid >= d) ? s[tid - d] : 0;
        __syncthreads();
        acc += add;
        s[tid] = acc;
        __syncthreads();
    }
    int excl = acc - cv;
    lcur[tid] = excl;
    const int node = (b << 8) + tid;
    if (node < NN) {
        cnt[node] = cv;
        cursor[node] = base + excl + cv;            // END cursor (start = end - cnt)
        dinv[node] = rsqrtf((float)(cv + 1));       // +1 self-loop
    }
    __syncthreads();
    for (int j = tid; j < nb; j += 256) {
        unsigned v = rec[base + j];
        int pos = atomicAdd(&lcur[v >> 24], 1);     // LDS atomic
        lde[pos] = (int)(v & 0xFFFFFFu);
    }
    __syncthreads();
    for (int j = tid; j < nb; j += 256) eidx[base + j] = lde[j];
}

// ---- fused prep: xh[i] = bf16(x[i]*dinv[i]) ; pack W1,W2 ----
__global__ void k_prep(const float2* __restrict__ x, const float* __restrict__ dinv,
                       unsigned* __restrict__ xh,
                       const float* __restrict__ W1, const float* __restrict__ W2,
                       __hip_bfloat16* __restrict__ W1p, __hip_bfloat16* __restrict__ W2p) {
    if (blockIdx.x < XB) {
        int idx = blockIdx.x * 256 + threadIdx.x;   // NN*64 dword-pairs
        if (idx < NN * 64) {
            float d = dinv[idx >> 6];
            float2 v = x[idx];
            xh[idx] = (unsigned)f2bf(v.x * d) | ((unsigned)f2bf(v.y * d) << 16);
        }
    } else {
        int idx = (blockIdx.x - XB) * 256 + threadIdx.x;
        if (idx < F1 * F2) {
            int k = idx / F2, col = idx - (idx / F2) * F2;
            int k8 = k >> 3, j = k & 7;
            W1p[((size_t)(k8 * F2 + col) << 3) + j] = __float2bfloat16(W1[(size_t)k * F2 + col]);
        } else if (idx < F1 * F2 + F2 * 48) {
            int i2 = idx - F1 * F2;
            int k = i2 / 48, col = i2 - (i2 / 48) * 48;
            int k8 = k >> 3, j = k & 7;
            float v = (col < F3) ? W2[(size_t)k * F3 + col] : 0.0f;
            W2p[((size_t)(k8 * 48 + col) << 3) + j] = __float2bfloat16(v);
        }
    }
}

// ---- layer-1 pull aggregation: 8 edge-rows in flight per wave ----
__global__ __launch_bounds__(256) void k_agg1(const int* __restrict__ cursor,
                                              const int* __restrict__ cnt,
                                              const int* __restrict__ eidx,
                                              const float* __restrict__ dinv,
                                              const unsigned* __restrict__ xh,
                                              unsigned* __restrict__ agg) {
    int node = blockIdx.x * 4 + (threadIdx.x >> 6);
    int lane = threadIdx.x & 63;
    if (node >= NN) return;
    unsigned vs = xh[((size_t)node << 6) + lane];
    float a0 = bflo(vs), a1 = bfhi(vs);
    int n = cnt[node];
    int s = cursor[node] - n;
    int k = 0;
    for (; k + 7 < n; k += 8) {
        int r0 = eidx[s + k + 0], r1 = eidx[s + k + 1];
        int r2 = eidx[s + k + 2], r3 = eidx[s + k + 3];
        int r4 = eidx[s + k + 4], r5 = eidx[s + k + 5];
        int r6 = eidx[s + k + 6], r7 = eidx[s + k + 7];
        unsigned v0 = xh[((size_t)r0 << 6) + lane];
        unsigned v1 = xh[((size_t)r1 << 6) + lane];
        unsigned v2 = xh[((size_t)r2 << 6) + lane];
        unsigned v3 = xh[((size_t)r3 << 6) + lane];
        unsigned v4 = xh[((size_t)r4 << 6) + lane];
        unsigned v5 = xh[((size_t)r5 << 6) + lane];
        unsigned v6 = xh[((size_t)r6 << 6) + lane];
        unsigned v7 = xh[((size_t)r7 << 6) + lane];
        a0 += bflo(v0); a1 += bfhi(v0);
        a0 += bflo(v1); a1 += bfhi(v1);
        a0 += bflo(v2); a1 += bfhi(v2);
        a0 += bflo(v3); a1 += bfhi(v3);
        a0 += bflo(v4); a1 += bfhi(v4);
        a0 += bflo(v5); a1 += bfhi(v5);
        a0 += bflo(v6); a1 += bfhi(v6);
        a0 += bflo(v7); a1 += bfhi(v7);
    }
    for (; k + 3 < n; k += 4) {
        int r0 = eidx[s + k + 0], r1 = eidx[s + k + 1];
        int r2 = eidx[s + k + 2], r3 = eidx[s + k + 3];
        unsigned v0 = xh[((size_t)r0 << 6) + lane];
        unsigned v1 = xh[((size_t)r1 << 6) + lane];
        unsigned v2 = xh[((size_t)r2 << 6) + lane];
        unsigned v3 = xh[((size_t)r3 << 6) + lane];
        a0 += bflo(v0); a1 += bfhi(v0);
        a0 += bflo(v1); a1 += bfhi(v1);
        a0 += bflo(v2); a1 += bfhi(v2);
        a0 += bflo(v3); a1 += bfhi(v3);
    }
    for (; k < n; ++k) {
        unsigned v0 = xh[((size_t)eidx[s + k] << 6) + lane];
        a0 += bflo(v0); a1 += bfhi(v0);
    }
    float d = dinv[node];
    agg[((size_t)node << 6) + lane] = (unsigned)f2bf(a0 * d) | ((unsigned)f2bf(a1 * d) << 16);
}

// ---- fused MFMA GEMM1 + ReLU + GEMM2; tg rows padded to 64 bf16 (one line) ----
__global__ __launch_bounds__(256) void k_gemm_mfma(
    const __hip_bfloat16* __restrict__ agg, const __hip_bfloat16* __restrict__ W1p,
    const float* __restrict__ b1, const __hip_bfloat16* __restrict__ W2p,
    const float* __restrict__ dinv, unsigned short* __restrict__ tg) {
    __shared__ __hip_bfloat16 h_s[MROWS][F2 + 8];   // 33 KB
    const int i0   = blockIdx.x * MROWS;
    const int wave = threadIdx.x >> 6;
    const int lane = threadIdx.x & 63;
    const int m = lane & 15, q = lane >> 4;
    const int rowA = i0 + wave * 16 + m;

    f32x4 acc[16];
#pragma unroll
    for (int c = 0; c < 16; ++c) acc[c] = (f32x4){0.f, 0.f, 0.f, 0.f};

#pragma unroll
    for (int s = 0; s < 4; ++s) {           // k = 32s + 8q + j
        bf16x8 a;
#pragma unroll
        for (int j = 0; j < 8; ++j) a[j] = (__bf16)0.0f;
        if (rowA < NN) a = *(const bf16x8*)(agg + (size_t)rowA * F1 + s * 32 + q * 8);
        const __hip_bfloat16* bp = W1p + ((size_t)(4 * s + q) * F2) * 8;
#pragma unroll
        for (int c = 0; c < 16; ++c) {
            bf16x8 b = *(const bf16x8*)(bp + ((size_t)(c * 16 + m) << 3));
            acc[c] = __builtin_amdgcn_mfma_f32_16x16x32_bf16(a, b, acc[c], 0, 0, 0);
        }
    }

#pragma unroll
    for (int c = 0; c < 16; ++c) {
        int col = c * 16 + m;
        float bj = b1[col];
#pragma unroll
        for (int r = 0; r < 4; ++r) {
            int lr = wave * 16 + q * 4 + r;
            h_s[lr][col] = __float2bfloat16(fmaxf(acc[c][r] + bj, 0.0f));
        }
    }
    __syncthreads();

    f32x4 acc2[3];
#pragma unroll
    for (int c = 0; c < 3; ++c) acc2[c] = (f32x4){0.f, 0.f, 0.f, 0.f};

#pragma unroll
    for (int s = 0; s < 8; ++s) {
        bf16x8 a = *(const bf16x8*)(&h_s[wave * 16 + m][s * 32 + q * 8]);
        const __hip_bfloat16* bp = W2p + ((size_t)(4 * s + q) * 48) * 8;
#pragma unroll
        for (int c = 0; c < 3; ++c) {
            bf16x8 b = *(const bf16x8*)(bp + ((size_t)(c * 16 + m) << 3));
            acc2[c] = __builtin_amdgcn_mfma_f32_16x16x32_bf16(a, b, acc2[c], 0, 0, 0);
        }
    }

#pragma unroll
    for (int c = 0; c < 3; ++c) {
        int col = c * 16 + m;
        if (col < F3) {
#pragma unroll
            for (int r = 0; r < 4; ++r) {
                int grow = i0 + wave * 16 + q * 4 + r;
                if (grow < NN)
                    tg[((size_t)grow << 6) + col] = f2bf(acc2[c][r] * dinv[grow]);
            }
        }
    }
}

// ---- layer-2 pull aggregation: 8 line-rows in flight per wave ----
__global__ __launch_bounds__(256) void k_agg2(const int* __restrict__ cursor,
                                              const int* __restrict__ cnt,
                                              const int* __restrict__ eidx,
                                              const float* __restrict__ dinv,
                                              const unsigned short* __restrict__ tg,
                                              const float* __restrict__ b2,
                                              float* __restrict__ out) {
    int node = blockIdx.x * 4 + (threadIdx.x >> 6);
    int lane = threadIdx.x & 63;
    if (node >= NN || lane >= F3) return;
    float a = __uint_as_float((unsigned)tg[((size_t)node << 6) + lane] << 16);
    int n = cnt[node];
    int s = cursor[node] - n;
    int k = 0;
    for (; k + 7 < n; k += 8) {
        int r0 = eidx[s + k + 0], r1 = eidx[s + k + 1];
        int r2 = eidx[s + k + 2], r3 = eidx[s + k + 3];
        int r4 = eidx[s + k + 4], r5 = eidx[s + k + 5];
        int r6 = eidx[s + k + 6], r7 = eidx[s + k + 7];
        unsigned short w0 = tg[((size_t)r0 << 6) + lane];
        unsigned short w1 = tg[((size_t)r1 << 6) + lane];
        unsigned short w2 = tg[((size_t)r2 << 6) + lane];
        unsigned short w3 = tg[((size_t)r3 << 6) + lane];
        unsigned short w4 = tg[((size_t)r4 << 6) + lane];
        unsigned short w5 = tg[((size_t)r5 << 6) + lane];
        unsigned short w6 = tg[((size_t)r6 << 6) + lane];
        unsigned short w7 = tg[((size_t)r7 << 6) + lane];
        a += __uint_as_float((unsigned)w0 << 16);
        a += __uint_as_float((unsigned)w1 << 16);
        a += __uint_as_float((unsigned)w2 << 16);
        a += __uint_as_float((unsigned)w3 << 16);
        a += __uint_as_float((unsigned)w4 << 16);
        a += __uint_as_float((unsigned)w5 << 16);
        a += __uint_as_float((unsigned)w6 << 16);
        a += __uint_as_float((unsigned)w7 << 16);
    }
    for (; k + 3 < n; k += 4) {
        int r0 = eidx[s + k + 0], r1 = eidx[s + k + 1];
        int r2 = eidx[s + k + 2], r3 = eidx[s + k + 3];
        unsigned short w0 = tg[((size_t)r0 << 6) + lane];
        unsigned short w1 = tg[((size_t)r1 << 6) + lane];
        unsigned short w2 = tg[((size_t)r2 << 6) + lane];
        unsigned short w3 = tg[((size_t)r3 << 6) + lane];
        a += __uint_as_float((unsigned)w0 << 16);
        a += __uint_as_float((unsigned)w1 << 16);
        a += __uint_as_float((unsigned)w2 << 16);
        a += __uint_as_float((unsigned)w3 << 16);
    }
    for (; k < n; ++k)
        a += __uint_as_float((unsigned)tg[((size_t)eidx[s + k] << 6) + lane] << 16);
    out[(size_t)node * F3 + lane] = dinv[node] * a + b2[lane];
}

extern "C" void kernel_launch(void* const* d_in, const int* in_sizes, int n_in,
                              void* d_out, int out_size, void* d_ws, size_t ws_size,
                              hipStream_t stream) {
    const float* x  = (const float*)d_in[0];
    const int*   ei = (const int*)d_in[1];
    const float* W1 = (const float*)d_in[2];
    const float* b1 = (const float*)d_in[3];
    const float* W2 = (const float*)d_in[4];
    const float* b2 = (const float*)d_in[5];
    float* out = (float*)d_out;

    const int* row = ei;
    const int* col = ei + EE;

    // ws: cnt[N] | cursor[N] | dinv[N] | hist[NBUK*NBLK] | bintot | binbase
    //     | eidx[E] | xh[N*64 u32] | agg[N*64 u32] | W1p | W2p         ~58 MB
    // overlays: rec (E u32) on agg (dead until k_agg1); tg (N*64 bf16) on xh
    // (dead after k_agg1, written by k_gemm, read by k_agg2).
    int* cnt     = (int*)d_ws;
    int* cursor  = cnt + NN;
    float* dinv  = (float*)(cursor + NN);
    int* hist    = (int*)(dinv + NN);
    int* bintot  = hist + NBUK * NBLK;
    int* binbase = bintot + NBUK;
    int* eidx    = binbase + (NBUK + 1) + 7;   // alignment slack
    unsigned* xh  = (unsigned*)(eidx + EE);
    unsigned* agg = xh + (size_t)NN * 64;
    unsigned* rec = agg;                               // overlay
    unsigned short* tg = (unsigned short*)xh;          // overlay
    __hip_bfloat16* W1p = (__hip_bfloat16*)(agg + (size_t)NN * 64);
    __hip_bfloat16* W2p = W1p + (size_t)F1 * F2;

    k_hist    <<<NBLK, 256, 0, stream>>>(col, hist);
    k_scanbin <<<NBUK, NBLK, 0, stream>>>(hist, bintot);
    k_scanbase<<<1, 512, 0, stream>>>(bintot, binbase);
    k_scat    <<<NBLK, 256, 0, stream>>>(row, col, hist, binbase, rec);
    k_csr     <<<NBUK, 256, 0, stream>>>(binbase, rec, eidx, cnt, cursor, dinv);

    k_prep<<<XB + (F1 * F2 + F2 * 48 + 255) / 256, 256, 0, stream>>>(
        (const float2*)x, dinv, xh, W1, W2, W1p, W2p);

    k_agg1<<<(NN + 3) / 4, 256, 0, stream>>>(cursor, cnt, eidx, dinv, xh, agg);
    k_gemm_mfma<<<(NN + MROWS - 1) / MROWS, 256, 0, stream>>>(
        (const __hip_bfloat16*)agg, W1p, b1, W2p, dinv, tg);
    k_agg2<<<(NN + 3) / 4, 256, 0, stream>>>(cursor, cnt, eidx, dinv, tg, b2, out);
}